// Round 21
// baseline (248.683 us; speedup 1.0000x reference)
//
#include <hip/hip_runtime.h>
#include <math.h>

#define BB 1024
#define DD 128
#define QQ 65536
#define CHUNK 32
#define THREADS 256
#define COLS_PER_BLOCK 128
#define F2G (BB / COLS_PER_BLOCK)   // 8
#define NSLICES 256
#define INV_T 14.285714285714286f
#define SCALE 20.609929155556627f   // (1/T) * log2(e)
#define LN2F 0.6931471805599453f

typedef short short8 __attribute__((ext_vector_type(8)));
typedef float f32x4  __attribute__((ext_vector_type(4)));

#if __has_builtin(__builtin_amdgcn_exp2f)
#define EXP2F(x) __builtin_amdgcn_exp2f(x)
#else
#define EXP2F(x) exp2f(x)
#endif

// pack two f32 -> two bf16 (round-half-up) in ONE v_perm_b32:
// low16(result)=bf16(a0), high16(result)=bf16(a1)
static __device__ __forceinline__ unsigned pkbf16(float a0, float a1) {
    union { float f; unsigned u; } x0, x1;
    x0.f = a0; x1.f = a1;
#if __has_builtin(__builtin_amdgcn_perm)
    return __builtin_amdgcn_perm(x1.u + 0x8000u, x0.u + 0x8000u, 0x07060302u);
#else
    return ((x0.u + 0x8000u) >> 16) | ((x1.u + 0x8000u) & 0xFFFF0000u);
#endif
}

static __device__ __forceinline__ short8 pack8(float4 x, float4 y) { // unscaled
    union { unsigned u[4]; short8 s; } r;
    r.u[0] = pkbf16(x.x, x.y);
    r.u[1] = pkbf16(x.z, x.w);
    r.u[2] = pkbf16(y.x, y.y);
    r.u[3] = pkbf16(y.z, y.w);
    return r.s;
}
static __device__ __forceinline__ short8 pack8s(float4 x, float4 y) { // * SCALE
    union { unsigned u[4]; short8 s; } r;
    r.u[0] = pkbf16(x.x * SCALE, x.y * SCALE);
    r.u[1] = pkbf16(x.z * SCALE, x.w * SCALE);
    r.u[2] = pkbf16(y.x * SCALE, y.y * SCALE);
    r.u[3] = pkbf16(y.z * SCALE, y.w * SCALE);
    return r.s;
}

// ---------- main: r20 verbatim + __launch_bounds__(256,8) to cap VGPR at 64 ----------
// m69: HW wave slots halve at VGPR=64 step; 72->64 doubles resident waves.
template<int REMAP>
__global__ __launch_bounds__(THREADS, 8)
void supcon_main(const float* __restrict__ features, const int* __restrict__ labels,
                 const float* __restrict__ queue, const int* __restrict__ queue_labels,
                 float* __restrict__ stats, int nslices)
{
    __shared__ int4 ldsbuf[2][512];   // 2 x 8KB bf16 A-chunks [32][128], swizzled

    const int tid = threadIdx.x;
    const int l = tid & 63, w = tid >> 6;
    const int bid = blockIdx.x;
    int slice, f2g;
    if (REMAP) {
        f2g   = (bid >> 3) & 7;
        slice = (bid & 7) + 8 * (bid >> 6);
    } else {
        slice = bid % nslices;
        f2g   = bid / nslices;
    }
    const int sliceRows = QQ / nslices;
    const int nchunks = sliceRows / CHUNK;
    const int colbase = f2g * COLS_PER_BLOCK + w * 32;

    // stationary B operand: 2x16 f2 cols, scaled bf16 packed from f32 (once per block)
    short8 bf[2][4];
    int mylab[2];
#pragma unroll
    for (int b = 0; b < 2; ++b) {
        int r = colbase + b * 16 + (l & 15);
        mylab[b] = labels[r];
        const float* fp = features + (size_t)r * 2 * DD + DD + ((l >> 4) * 8);
#pragma unroll
        for (int kk = 0; kk < 4; ++kk) {
            float4 x = *reinterpret_cast<const float4*>(fp + kk * 32);
            float4 y = *reinterpret_cast<const float4*>(fp + kk * 32 + 4);
            bf[b][kk] = pack8s(x, y);
        }
    }

    float tot[2]  = {0.f,0.f};
    float pose[2] = {0.f,0.f};
    float psum[2] = {0.f,0.f};
    float npos[2] = {0.f,0.f};

    const int srow = tid >> 3, sseg = tid & 7;
    const int swzs = (srow & 7) << 4;
    const int j0base = slice * sliceRows;

    // prologue: stage chunk 0 (f32 -> bf16 in staging)
    {
        int j = j0base + srow;
        const float* src = ((j < BB) ? (features + (size_t)j * 2 * DD)
                                     : (queue + (size_t)(j - BB) * DD)) + sseg * 16;
        float4 p0 = reinterpret_cast<const float4*>(src)[0];
        float4 p1 = reinterpret_cast<const float4*>(src)[1];
        float4 p2 = reinterpret_cast<const float4*>(src)[2];
        float4 p3 = reinterpret_cast<const float4*>(src)[3];
        char* base = (char*)&ldsbuf[0][0] + srow * 256;
        int cb0 = (sseg * 32) ^ swzs;
        *reinterpret_cast<short8*>(base + cb0)        = pack8(p0, p1);
        *reinterpret_cast<short8*>(base + (cb0 ^ 16)) = pack8(p2, p3);
    }

    int cur = 0;
    for (int c = 0; c < nchunks; ++c) {
        __syncthreads();
        const int cj0 = j0base + c * CHUNK;
        const bool havenext = (c + 1 < nchunks);

        // issue next chunk's loads early (T14)
        float4 p0, p1, p2, p3;
        if (havenext) {
            int j = cj0 + CHUNK + srow;
            const float* src = ((j < BB) ? (features + (size_t)j * 2 * DD)
                                         : (queue + (size_t)(j - BB) * DD)) + sseg * 16;
            p0 = reinterpret_cast<const float4*>(src)[0];
            p1 = reinterpret_cast<const float4*>(src)[1];
            p2 = reinterpret_cast<const float4*>(src)[2];
            p3 = reinterpret_cast<const float4*>(src)[3];
        }

        // compute from buf[cur]
        const char* abase = (const char*)&ldsbuf[cur][0];
#pragma unroll
        for (int t2 = 0; t2 < 2; ++t2) {
            const int row = t2 * 16 + (l & 15);
            const char* rbase = abase + row * 256;
            const int g16 = (l >> 4) * 16;
            const int swz = (row & 7) << 4;
            const int j0 = cj0 + t2 * 16 + ((l >> 4) << 2);

            int4 ql4 = (j0 < BB) ? *reinterpret_cast<const int4*>(labels + j0)
                                 : *reinterpret_cast<const int4*>(queue_labels + (j0 - BB));
            const int* ql = reinterpret_cast<const int*>(&ql4);

            f32x4 acc[2];
#pragma unroll
            for (int b = 0; b < 2; ++b) acc[b] = f32x4{0.f,0.f,0.f,0.f};
#pragma unroll
            for (int kk = 0; kk < 4; ++kk) {
                short8 a = *reinterpret_cast<const short8*>(rbase + ((kk * 64 + g16) ^ swz));
#pragma unroll
                for (int b = 0; b < 2; ++b)
                    acc[b] = __builtin_amdgcn_mfma_f32_16x16x32_bf16(a, bf[b][kk], acc[b], 0, 0, 0);
            }
#pragma unroll
            for (int b = 0; b < 2; ++b) {
#pragma unroll
                for (int reg = 0; reg < 4; ++reg) {
                    float a = acc[b][reg];
                    float e = EXP2F(a);                 // a = s * log2(e); |a| <= ~20.6
                    float pf = (ql[reg] == mylab[b]) ? 1.0f : 0.0f;
                    tot[b]  += e;
                    pose[b]  = fmaf(pf, e, pose[b]);
                    psum[b]  = fmaf(pf, a, psum[b]);
                    npos[b] += pf;
                }
            }
        }

        // write next chunk into the other buffer (loads have landed)
        if (havenext) {
            char* base = (char*)&ldsbuf[cur ^ 1][0] + srow * 256;
            int cb0 = (sseg * 32) ^ swzs;
            *reinterpret_cast<short8*>(base + cb0)        = pack8(p0, p1);
            *reinterpret_cast<short8*>(base + (cb0 ^ 16)) = pack8(p2, p3);
            cur ^= 1;
        }
    }

#pragma unroll
    for (int b = 0; b < 2; ++b) {
#pragma unroll
        for (int off = 16; off <= 32; off <<= 1) {
            tot[b]  += __shfl_xor(tot[b],  off);
            pose[b] += __shfl_xor(pose[b], off);
            psum[b] += __shfl_xor(psum[b], off);
            npos[b] += __shfl_xor(npos[b], off);
        }
    }
    if ((l >> 4) == 0) {
#pragma unroll
        for (int b = 0; b < 2; ++b) {
            float4 v; v.x = tot[b]; v.y = pose[b]; v.z = psum[b]; v.w = npos[b];
            *reinterpret_cast<float4*>(
                stats + ((size_t)(colbase + b * 16 + l) * nslices + slice) * 4) = v;
        }
    }
}

// ---------- F1: stats reduce + inline srr dot -> per-block partials ----------
__global__ __launch_bounds__(256)
void f1_rows(const float* __restrict__ stats, const float* __restrict__ features,
             float* __restrict__ partials, int nslices)
{
    __shared__ float red[4][2];
    int wv = threadIdx.x >> 6, lane = threadIdx.x & 63;
    int r = blockIdx.x * 4 + wv;
    float tot = 0.f, pose = 0.f, ps = 0.f, np = 0.f;
    for (int s = lane; s < nslices; s += 64) {
        float4 v = reinterpret_cast<const float4*>(stats)[(size_t)r * nslices + s];
        tot += v.x; pose += v.y; ps += v.z; np += v.w;
    }
    // inline srr: dot(f1[r], f2[r]) over 128 elems, float2 per lane
    const float* fr = features + (size_t)r * 2 * DD;
    float2 vb = reinterpret_cast<const float2*>(fr)[lane];
    float2 va = reinterpret_cast<const float2*>(fr + DD)[lane];
    float d = va.x * vb.x + va.y * vb.y;
#pragma unroll
    for (int off = 32; off > 0; off >>= 1) {
        tot  += __shfl_xor(tot,  off);
        pose += __shfl_xor(pose, off);
        ps   += __shfl_xor(ps,   off);
        np   += __shfl_xor(np,   off);
        d    += __shfl_xor(d,    off);
    }
    if (lane == 0) {
        float neg  = tot - pose;
        float srow = d * INV_T;                // exact diag logit
        float trip = srow - logf(tot - expf(srow));
        float wgt  = 1.f / (np - 1.f);         // np includes diag
        float mlpp = (ps * LN2F - srow) * wgt - logf(neg);
        red[wv][0] = trip; red[wv][1] = mlpp;
    }
    __syncthreads();
    if (threadIdx.x == 0) {
        partials[blockIdx.x * 2]     = red[0][0] + red[1][0] + red[2][0] + red[3][0];
        partials[blockIdx.x * 2 + 1] = red[0][1] + red[1][1] + red[2][1] + red[3][1];
    }
}

// ---------- F2: sum 256 partials, write 3 outputs ----------
__global__ __launch_bounds__(256)
void f2_out(const float* __restrict__ partials, float* __restrict__ out)
{
    __shared__ float red[4][2];
    int wv = threadIdx.x >> 6, lane = threadIdx.x & 63;
    float2 v = reinterpret_cast<const float2*>(partials)[threadIdx.x];
    float a = v.x, b = v.y;
#pragma unroll
    for (int off = 32; off > 0; off >>= 1) {
        a += __shfl_xor(a, off);
        b += __shfl_xor(b, off);
    }
    if (lane == 0) { red[wv][0] = a; red[wv][1] = b; }
    __syncthreads();
    if (threadIdx.x == 0) {
        float aT = red[0][0] + red[1][0] + red[2][0] + red[3][0];
        float aM = red[0][1] + red[1][1] + red[2][1] + red[3][1];
        float selfl  = -aT / (float)BB;
        float classl = -aM / (float)BB;
        out[0] = 0.5f * (selfl + classl);
        out[1] = selfl;
        out[2] = classl;
    }
}

extern "C" void kernel_launch(void* const* d_in, const int* in_sizes, int n_in,
                              void* d_out, int out_size, void* d_ws, size_t ws_size,
                              hipStream_t stream)
{
    const float* features     = (const float*)d_in[0];
    const int*   labels       = (const int*)  d_in[1];
    const float* queue        = (const float*)d_in[2];
    const int*   queue_labels = (const int*)  d_in[3];
    char* ws = (char*)d_ws;

    const size_t partials_sz = 2048;
    int nslices = NSLICES;
    while ((size_t)BB * nslices * 16 + partials_sz > ws_size && nslices > 8)
        nslices >>= 1;
    size_t stats_sz = (size_t)BB * nslices * 16;

    float* stats    = (float*)ws;
    float* partials = (float*)(ws + stats_sz);

    if (nslices == NSLICES)
        supcon_main<1><<<dim3(F2G * NSLICES), dim3(THREADS), 0, stream>>>(
            features, labels, queue, queue_labels, stats, NSLICES);
    else
        supcon_main<0><<<dim3(F2G * nslices), dim3(THREADS), 0, stream>>>(
            features, labels, queue, queue_labels, stats, nslices);

    f1_rows<<<dim3(BB / 4), dim3(256), 0, stream>>>(stats, features, partials, nslices);
    f2_out<<<dim3(1), dim3(256), 0, stream>>>(partials, (float*)d_out);
}

// Round 22
// 55.036 us; speedup vs baseline: 4.5185x; 4.5185x over previous
//
#include <hip/hip_runtime.h>
#include <math.h>

#define BB 1024
#define DD 128
#define QQ 65536
#define CHUNK 32
#define THREADS 256
#define COLS_PER_BLOCK 128
#define F2G (BB / COLS_PER_BLOCK)   // 8
#define NSLICES 256
#define INV_T 14.285714285714286f
#define SCALE 20.609929155556627f   // (1/T) * log2(e)
#define LN2F 0.6931471805599453f

typedef short short8 __attribute__((ext_vector_type(8)));
typedef float f32x4  __attribute__((ext_vector_type(4)));

#if __has_builtin(__builtin_amdgcn_exp2f)
#define EXP2F(x) __builtin_amdgcn_exp2f(x)
#else
#define EXP2F(x) exp2f(x)
#endif

// pack two f32 -> two bf16 (round-half-up) in ONE v_perm_b32:
// low16(result)=bf16(a0), high16(result)=bf16(a1)
static __device__ __forceinline__ unsigned pkbf16(float a0, float a1) {
    union { float f; unsigned u; } x0, x1;
    x0.f = a0; x1.f = a1;
#if __has_builtin(__builtin_amdgcn_perm)
    return __builtin_amdgcn_perm(x1.u + 0x8000u, x0.u + 0x8000u, 0x07060302u);
#else
    return ((x0.u + 0x8000u) >> 16) | ((x1.u + 0x8000u) & 0xFFFF0000u);
#endif
}

static __device__ __forceinline__ short8 pack8(float4 x, float4 y) { // unscaled
    union { unsigned u[4]; short8 s; } r;
    r.u[0] = pkbf16(x.x, x.y);
    r.u[1] = pkbf16(x.z, x.w);
    r.u[2] = pkbf16(y.x, y.y);
    r.u[3] = pkbf16(y.z, y.w);
    return r.s;
}
static __device__ __forceinline__ short8 pack8s(float4 x, float4 y) { // * SCALE
    union { unsigned u[4]; short8 s; } r;
    r.u[0] = pkbf16(x.x * SCALE, x.y * SCALE);
    r.u[1] = pkbf16(x.z * SCALE, x.w * SCALE);
    r.u[2] = pkbf16(y.x * SCALE, y.y * SCALE);
    r.u[3] = pkbf16(y.z * SCALE, y.w * SCALE);
    return r.s;
}

// ---------- main: self-contained; L2-temporal bid remap; depth-1 T14 pipeline ----------
// bid = (s%8) + 8*f2g + 64*(s/8): readers of slice s share an XCD AND are
// consecutive in launch order -> slice fetched from HBM once, L2-served 7x.
// NOTE: no __launch_bounds__ min-waves arg — any VGPR forcing spills (r8/r21).
template<int REMAP>
__global__ __launch_bounds__(THREADS)
void supcon_main(const float* __restrict__ features, const int* __restrict__ labels,
                 const float* __restrict__ queue, const int* __restrict__ queue_labels,
                 float* __restrict__ stats, int nslices)
{
    __shared__ int4 ldsbuf[2][512];   // 2 x 8KB bf16 A-chunks [32][128], swizzled

    const int tid = threadIdx.x;
    const int l = tid & 63, w = tid >> 6;
    const int bid = blockIdx.x;
    int slice, f2g;
    if (REMAP) {
        f2g   = (bid >> 3) & 7;
        slice = (bid & 7) + 8 * (bid >> 6);
    } else {
        slice = bid % nslices;
        f2g   = bid / nslices;
    }
    const int sliceRows = QQ / nslices;
    const int nchunks = sliceRows / CHUNK;
    const int colbase = f2g * COLS_PER_BLOCK + w * 32;

    // stationary B operand: 2x16 f2 cols, scaled bf16 packed from f32 (once per block)
    short8 bf[2][4];
    int mylab[2];
#pragma unroll
    for (int b = 0; b < 2; ++b) {
        int r = colbase + b * 16 + (l & 15);
        mylab[b] = labels[r];
        const float* fp = features + (size_t)r * 2 * DD + DD + ((l >> 4) * 8);
#pragma unroll
        for (int kk = 0; kk < 4; ++kk) {
            float4 x = *reinterpret_cast<const float4*>(fp + kk * 32);
            float4 y = *reinterpret_cast<const float4*>(fp + kk * 32 + 4);
            bf[b][kk] = pack8s(x, y);
        }
    }

    float tot[2]  = {0.f,0.f};
    float pose[2] = {0.f,0.f};
    float psum[2] = {0.f,0.f};
    float npos[2] = {0.f,0.f};

    const int srow = tid >> 3, sseg = tid & 7;
    const int swzs = (srow & 7) << 4;
    const int j0base = slice * sliceRows;

    // prologue: stage chunk 0 (f32 -> bf16 in staging)
    {
        int j = j0base + srow;
        const float* src = ((j < BB) ? (features + (size_t)j * 2 * DD)
                                     : (queue + (size_t)(j - BB) * DD)) + sseg * 16;
        float4 p0 = reinterpret_cast<const float4*>(src)[0];
        float4 p1 = reinterpret_cast<const float4*>(src)[1];
        float4 p2 = reinterpret_cast<const float4*>(src)[2];
        float4 p3 = reinterpret_cast<const float4*>(src)[3];
        char* base = (char*)&ldsbuf[0][0] + srow * 256;
        int cb0 = (sseg * 32) ^ swzs;
        *reinterpret_cast<short8*>(base + cb0)        = pack8(p0, p1);
        *reinterpret_cast<short8*>(base + (cb0 ^ 16)) = pack8(p2, p3);
    }

    int cur = 0;
    for (int c = 0; c < nchunks; ++c) {
        __syncthreads();
        const int cj0 = j0base + c * CHUNK;
        const bool havenext = (c + 1 < nchunks);

        // issue next chunk's loads early (T14)
        float4 p0, p1, p2, p3;
        if (havenext) {
            int j = cj0 + CHUNK + srow;
            const float* src = ((j < BB) ? (features + (size_t)j * 2 * DD)
                                         : (queue + (size_t)(j - BB) * DD)) + sseg * 16;
            p0 = reinterpret_cast<const float4*>(src)[0];
            p1 = reinterpret_cast<const float4*>(src)[1];
            p2 = reinterpret_cast<const float4*>(src)[2];
            p3 = reinterpret_cast<const float4*>(src)[3];
        }

        // compute from buf[cur]
        const char* abase = (const char*)&ldsbuf[cur][0];
#pragma unroll
        for (int t2 = 0; t2 < 2; ++t2) {
            const int row = t2 * 16 + (l & 15);
            const char* rbase = abase + row * 256;
            const int g16 = (l >> 4) * 16;
            const int swz = (row & 7) << 4;
            const int j0 = cj0 + t2 * 16 + ((l >> 4) << 2);

            int4 ql4 = (j0 < BB) ? *reinterpret_cast<const int4*>(labels + j0)
                                 : *reinterpret_cast<const int4*>(queue_labels + (j0 - BB));
            const int* ql = reinterpret_cast<const int*>(&ql4);

            f32x4 acc[2];
#pragma unroll
            for (int b = 0; b < 2; ++b) acc[b] = f32x4{0.f,0.f,0.f,0.f};
#pragma unroll
            for (int kk = 0; kk < 4; ++kk) {
                short8 a = *reinterpret_cast<const short8*>(rbase + ((kk * 64 + g16) ^ swz));
#pragma unroll
                for (int b = 0; b < 2; ++b)
                    acc[b] = __builtin_amdgcn_mfma_f32_16x16x32_bf16(a, bf[b][kk], acc[b], 0, 0, 0);
            }
#pragma unroll
            for (int b = 0; b < 2; ++b) {
#pragma unroll
                for (int reg = 0; reg < 4; ++reg) {
                    float a = acc[b][reg];
                    float e = EXP2F(a);                 // a = s * log2(e); |a| <= ~20.6
                    float pf = (ql[reg] == mylab[b]) ? 1.0f : 0.0f;
                    tot[b]  += e;
                    pose[b]  = fmaf(pf, e, pose[b]);
                    psum[b]  = fmaf(pf, a, psum[b]);
                    npos[b] += pf;
                }
            }
        }

        // write next chunk into the other buffer (loads have landed)
        if (havenext) {
            char* base = (char*)&ldsbuf[cur ^ 1][0] + srow * 256;
            int cb0 = (sseg * 32) ^ swzs;
            *reinterpret_cast<short8*>(base + cb0)        = pack8(p0, p1);
            *reinterpret_cast<short8*>(base + (cb0 ^ 16)) = pack8(p2, p3);
            cur ^= 1;
        }
    }

#pragma unroll
    for (int b = 0; b < 2; ++b) {
#pragma unroll
        for (int off = 16; off <= 32; off <<= 1) {
            tot[b]  += __shfl_xor(tot[b],  off);
            pose[b] += __shfl_xor(pose[b], off);
            psum[b] += __shfl_xor(psum[b], off);
            npos[b] += __shfl_xor(npos[b], off);
        }
    }
    if ((l >> 4) == 0) {
#pragma unroll
        for (int b = 0; b < 2; ++b) {
            float4 v; v.x = tot[b]; v.y = pose[b]; v.z = psum[b]; v.w = npos[b];
            *reinterpret_cast<float4*>(
                stats + ((size_t)(colbase + b * 16 + l) * nslices + slice) * 4) = v;
        }
    }
}

// ---------- F1: stats reduce + inline srr dot -> per-block partials ----------
__global__ __launch_bounds__(256)
void f1_rows(const float* __restrict__ stats, const float* __restrict__ features,
             float* __restrict__ partials, int nslices)
{
    __shared__ float red[4][2];
    int wv = threadIdx.x >> 6, lane = threadIdx.x & 63;
    int r = blockIdx.x * 4 + wv;
    float tot = 0.f, pose = 0.f, ps = 0.f, np = 0.f;
    for (int s = lane; s < nslices; s += 64) {
        float4 v = reinterpret_cast<const float4*>(stats)[(size_t)r * nslices + s];
        tot += v.x; pose += v.y; ps += v.z; np += v.w;
    }
    // inline srr: dot(f1[r], f2[r]) over 128 elems, float2 per lane
    const float* fr = features + (size_t)r * 2 * DD;
    float2 vb = reinterpret_cast<const float2*>(fr)[lane];
    float2 va = reinterpret_cast<const float2*>(fr + DD)[lane];
    float d = va.x * vb.x + va.y * vb.y;
#pragma unroll
    for (int off = 32; off > 0; off >>= 1) {
        tot  += __shfl_xor(tot,  off);
        pose += __shfl_xor(pose, off);
        ps   += __shfl_xor(ps,   off);
        np   += __shfl_xor(np,   off);
        d    += __shfl_xor(d,    off);
    }
    if (lane == 0) {
        float neg  = tot - pose;
        float srow = d * INV_T;                // exact diag logit
        float trip = srow - logf(tot - expf(srow));
        float wgt  = 1.f / (np - 1.f);         // np includes diag
        float mlpp = (ps * LN2F - srow) * wgt - logf(neg);
        red[wv][0] = trip; red[wv][1] = mlpp;
    }
    __syncthreads();
    if (threadIdx.x == 0) {
        partials[blockIdx.x * 2]     = red[0][0] + red[1][0] + red[2][0] + red[3][0];
        partials[blockIdx.x * 2 + 1] = red[0][1] + red[1][1] + red[2][1] + red[3][1];
    }
}

// ---------- F2: sum 256 partials, write 3 outputs ----------
__global__ __launch_bounds__(256)
void f2_out(const float* __restrict__ partials, float* __restrict__ out)
{
    __shared__ float red[4][2];
    int wv = threadIdx.x >> 6, lane = threadIdx.x & 63;
    float2 v = reinterpret_cast<const float2*>(partials)[threadIdx.x];
    float a = v.x, b = v.y;
#pragma unroll
    for (int off = 32; off > 0; off >>= 1) {
        a += __shfl_xor(a, off);
        b += __shfl_xor(b, off);
    }
    if (lane == 0) { red[wv][0] = a; red[wv][1] = b; }
    __syncthreads();
    if (threadIdx.x == 0) {
        float aT = red[0][0] + red[1][0] + red[2][0] + red[3][0];
        float aM = red[0][1] + red[1][1] + red[2][1] + red[3][1];
        float selfl  = -aT / (float)BB;
        float classl = -aM / (float)BB;
        out[0] = 0.5f * (selfl + classl);
        out[1] = selfl;
        out[2] = classl;
    }
}

extern "C" void kernel_launch(void* const* d_in, const int* in_sizes, int n_in,
                              void* d_out, int out_size, void* d_ws, size_t ws_size,
                              hipStream_t stream)
{
    const float* features     = (const float*)d_in[0];
    const int*   labels       = (const int*)  d_in[1];
    const float* queue        = (const float*)d_in[2];
    const int*   queue_labels = (const int*)  d_in[3];
    char* ws = (char*)d_ws;

    const size_t partials_sz = 2048;
    int nslices = NSLICES;
    while ((size_t)BB * nslices * 16 + partials_sz > ws_size && nslices > 8)
        nslices >>= 1;
    size_t stats_sz = (size_t)BB * nslices * 16;

    float* stats    = (float*)ws;
    float* partials = (float*)(ws + stats_sz);

    if (nslices == NSLICES)
        supcon_main<1><<<dim3(F2G * NSLICES), dim3(THREADS), 0, stream>>>(
            features, labels, queue, queue_labels, stats, NSLICES);
    else
        supcon_main<0><<<dim3(F2G * nslices), dim3(THREADS), 0, stream>>>(
            features, labels, queue, queue_labels, stats, nslices);

    f1_rows<<<dim3(BB / 4), dim3(256), 0, stream>>>(stats, features, partials, nslices);
    f2_out<<<dim3(1), dim3(256), 0, stream>>>(partials, (float*)d_out);
}